// Round 3
// baseline (95.779 us; speedup 1.0000x reference)
//
#include <hip/hip_runtime.h>
#include <math.h>

#define B_ 64
#define L_ 512
#define N_ 321
#define P_ 720
#define E_ 8
#define R_ 32
#define CID_ 32
#define H_ 64
#define ER_ 256

typedef __attribute__((ext_vector_type(8))) short bf16x8;
typedef __attribute__((ext_vector_type(4))) float f32x4;
typedef __attribute__((ext_vector_type(8))) unsigned short u16x8;
typedef __attribute__((ext_vector_type(4))) unsigned short u16x4;

// workspace layout (float offsets)
#define OFF_MEAN   0
#define OFF_SDEV   (B_*N_)                   // 20544
#define OFF_GATE   (2*B_*N_)                 // 41088
#define OFF_CS1    (OFF_GATE + N_*E_)        // 43656
#define OFF_BIASGT (OFF_CS1 + ER_)           // 43912
#define OFF_W1K    (OFF_BIASGT + P_*N_)      // 275032 (bf16 256*512 = 65536 floats)
#define OFF_W2T    (OFF_W1K + ER_*L_/2)      // 340568 (bf16 720*256 = 92160 floats)
#define OFF_HG     (OFF_W2T + P_*ER_/2)      // 432728 (bf16 64*321*256 = 2629632 floats)
// total ≈ 3.06M floats ≈ 12.3 MB

__device__ __forceinline__ unsigned short f2bf(float f) {
    unsigned u = __float_as_uint(f);
    u += 0x7fffu + ((u >> 16) & 1u);
    return (unsigned short)(u >> 16);
}
__device__ __forceinline__ float bf2f(unsigned short h) {
    return __uint_as_float(((unsigned)h) << 16);
}

// ---------------- router ----------------------------------------------------
__global__ void router_kernel(const float* __restrict__ ident,
                              const float* __restrict__ rw1, const float* __restrict__ rb1,
                              const float* __restrict__ rw2, const float* __restrict__ rb2,
                              float* __restrict__ gate) {
    int n = blockIdx.x;
    int t = threadIdx.x;  // 0..63
    __shared__ float hid[H_];
    __shared__ float lg[E_];
    float acc = rb1[t];
    #pragma unroll
    for (int c = 0; c < CID_; ++c)
        acc = fmaf(ident[n*CID_ + c], rw1[c*H_ + t], acc);
    hid[t] = fmaxf(acc, 0.f);
    __syncthreads();
    if (t < E_) {
        float a = rb2[t];
        #pragma unroll
        for (int h = 0; h < H_; ++h) a = fmaf(hid[h], rw2[h*E_ + t], a);
        lg[t] = a;
    }
    __syncthreads();
    if (t == 0) {
        float m = lg[0];
        #pragma unroll
        for (int e = 1; e < E_; ++e) m = fmaxf(m, lg[e]);
        float s = 0.f, ex[E_];
        #pragma unroll
        for (int e = 0; e < E_; ++e) { ex[e] = expf(lg[e] - m); s += ex[e]; }
        float inv = 1.f / s;
        #pragma unroll
        for (int e = 0; e < E_; ++e) gate[n*E_ + e] = ex[e] * inv;
    }
}

// ---------------- prep: w1k, w2t, cs1 (parallel), biasgT --------------------
__global__ void prep_kernel(const float* __restrict__ w1, const float* __restrict__ w2,
                            const float* __restrict__ gate, const float* __restrict__ bias,
                            unsigned short* __restrict__ w1k, unsigned short* __restrict__ w2t,
                            float* __restrict__ cs1, float* __restrict__ biasgT) {
    __shared__ float red[8][32];
    int bid = blockIdx.x, t = threadIdx.x;
    if (bid < 512) {                  // w1k [er][l]: 256*512
        int g = bid*256 + t;
        int er = g >> 9, l = g & 511;
        float v = w1[(size_t)(er >> 5)*(L_*R_) + (size_t)l*R_ + (er & 31)];
        w1k[g] = f2bf(v);
    } else if (bid < 1232) {          // w2t [p][er]: 720*256
        int g = (bid - 512)*256 + t;
        int p = g >> 8, er = g & 255;
        w2t[g] = f2bf(w2[(size_t)er*P_ + p]);
    } else if (bid < 1240) {          // cs1: 8 blocks, one expert each
        int e = bid - 1232;
        int q = t >> 5, r = t & 31;
        float s = 0.f;
        for (int l = q; l < L_; l += 8)
            s += bf2f(f2bf(w1[(size_t)e*(L_*R_) + (size_t)l*R_ + r]));
        red[q][r] = s;
        __syncthreads();
        if (q == 0) {
            #pragma unroll
            for (int qq = 1; qq < 8; ++qq) s += red[qq][r];
            cs1[e*32 + r] = s;
        }
    } else {                          // biasgT [p][n]: 720 blocks
        int p = bid - 1240;
        for (int n = t; n < N_; n += 256) {
            float a = 0.f;
            #pragma unroll
            for (int e = 0; e < E_; ++e)
                a = fmaf(gate[n*E_ + e], bias[(size_t)e*P_ + p], a);
            biasgT[(size_t)p*N_ + n] = a;
        }
    }
}

// ---------------- GEMM1: hg[b][n][er] = gate[n,e]*(sum_l w1k[er,l]*x[b,l,n] - mean*cs1)
// fused stats. BM=256, BN=64, BK=32, NT=16. Double-buffered, 1 barrier/step.
__global__ __launch_bounds__(512) void gemm1_kernel(
        const float* __restrict__ x, const unsigned short* __restrict__ w1k,
        const float* __restrict__ gate, const float* __restrict__ cs1,
        float* __restrict__ meanv, float* __restrict__ sdev,
        unsigned short* __restrict__ hg) {
    const int n0 = blockIdx.x * 64;
    const int b  = blockIdx.y;
    const int tid = threadIdx.x;
    const int lane = tid & 63;
    const int wave = tid >> 6;       // 0..7
    const int wm = wave >> 1;        // er-base = wm*64
    const int wn = wave & 1;         // n-base = wn*32

    __shared__ unsigned short As[2][256][40];   // 40960 B
    __shared__ unsigned short Bs[2][64][40];    // 10240 B
    __shared__ float red1[8][64];
    __shared__ float red2[8][64];
    __shared__ float meanS[64];

    const int arow = tid >> 1;          // 0..255
    const int acol = (tid & 1) * 16;    // 0/16
    const int xn = tid & 63;
    const int xkb = wave * 4;           // 0..28

    const float* xb = x + (size_t)b * L_ * N_;
    const int nglob = n0 + xn;
    const bool nvalid = (nglob < N_);

    float s1 = 0.f, s2 = 0.f;
    u16x8 a0, a1;
    float xv[4];

    f32x4 acc[4][2];
    #pragma unroll
    for (int i = 0; i < 4; ++i)
        #pragma unroll
        for (int j = 0; j < 2; ++j) acc[i][j] = (f32x4){0.f,0.f,0.f,0.f};

    // prologue: tile 0
    {
        a0 = *(const u16x8*)&w1k[(size_t)arow*L_ + acol];
        a1 = *(const u16x8*)&w1k[(size_t)arow*L_ + acol + 8];
        #pragma unroll
        for (int i = 0; i < 4; ++i)
            xv[i] = nvalid ? xb[(size_t)(xkb + i)*N_ + nglob] : 0.f;
        *(u16x8*)&As[0][arow][acol]   = a0;
        *(u16x8*)&As[0][arow][acol+8] = a1;
        u16x4 bp;
        #pragma unroll
        for (int i = 0; i < 4; ++i) {
            float v = xv[i]; s1 += v; s2 = fmaf(v, v, s2); bp[i] = f2bf(v);
        }
        *(u16x4*)&Bs[0][xn][xkb] = bp;
    }
    __syncthreads();

    for (int t = 0; t < 16; ++t) {
        const int cur = t & 1;
        if (t < 15) {
            int k0 = (t + 1) * 32;
            a0 = *(const u16x8*)&w1k[(size_t)arow*L_ + k0 + acol];
            a1 = *(const u16x8*)&w1k[(size_t)arow*L_ + k0 + acol + 8];
            #pragma unroll
            for (int i = 0; i < 4; ++i)
                xv[i] = nvalid ? xb[(size_t)(k0 + xkb + i)*N_ + nglob] : 0.f;
        }
        // compute current
        bf16x8 af[4], bfv[2];
        #pragma unroll
        for (int fm = 0; fm < 4; ++fm)
            af[fm] = *(const bf16x8*)&As[cur][wm*64 + fm*16 + (lane & 15)][(lane >> 4)*8];
        #pragma unroll
        for (int fn = 0; fn < 2; ++fn)
            bfv[fn] = *(const bf16x8*)&Bs[cur][wn*32 + fn*16 + (lane & 15)][(lane >> 4)*8];
        #pragma unroll
        for (int fm = 0; fm < 4; ++fm)
            #pragma unroll
            for (int fn = 0; fn < 2; ++fn)
                acc[fm][fn] = __builtin_amdgcn_mfma_f32_16x16x32_bf16(af[fm], bfv[fn], acc[fm][fn], 0, 0, 0);
        // stage next
        if (t < 15) {
            *(u16x8*)&As[cur^1][arow][acol]   = a0;
            *(u16x8*)&As[cur^1][arow][acol+8] = a1;
            u16x4 bp;
            #pragma unroll
            for (int i = 0; i < 4; ++i) {
                float v = xv[i]; s1 += v; s2 = fmaf(v, v, s2); bp[i] = f2bf(v);
            }
            *(u16x4*)&Bs[cur^1][xn][xkb] = bp;
        }
        __syncthreads();
    }

    // fused stats
    red1[wave][xn] = s1;
    red2[wave][xn] = s2;
    __syncthreads();
    if (tid < 64) {
        float a = 0.f, q = 0.f;
        #pragma unroll
        for (int kk = 0; kk < 8; ++kk) { a += red1[kk][tid]; q += red2[kk][tid]; }
        float mean = a * (1.f/L_);
        float var = (q - (float)L_*mean*mean) * (1.f/(L_-1));
        var = fmaxf(var, 0.f);
        float sd = sqrtf(var) + 1e-6f;
        meanS[tid] = mean;
        int n = n0 + tid;
        if (n < N_) { meanv[b*N_ + n] = mean; sdev[b*N_ + n] = sd; }
    }
    __syncthreads();

    // epilogue: hg[b][n][er] bf16
    #pragma unroll
    for (int fm = 0; fm < 4; ++fm) {
        int er0 = wm*64 + fm*16 + (lane >> 4)*4;
        int e = er0 >> 5;
        #pragma unroll
        for (int fn = 0; fn < 2; ++fn) {
            int nl = wn*32 + fn*16 + (lane & 15);
            int n = n0 + nl;
            if (n < N_) {
                float g = gate[n*E_ + e];
                float m = meanS[nl];
                u16x4 pk;
                #pragma unroll
                for (int j = 0; j < 4; ++j) {
                    float v = g * (acc[fm][fn][j] - m * cs1[er0 + j]);
                    pk[j] = f2bf(v);
                }
                *(u16x4*)&hg[((size_t)b*N_ + n)*ER_ + er0] = pk;
            }
        }
    }
}

// ---------------- GEMM2: out[b][p][n] = sum_er w2t[p,er]*hg[b,n,er] + biasgT[p,n]*sd + mean
// BM=128, BN=64, BK=64, NT=4. Double-buffered, 1 barrier/step.
__global__ __launch_bounds__(512) void gemm2_kernel(
        const unsigned short* __restrict__ hg, const unsigned short* __restrict__ w2t,
        const float* __restrict__ biasgT, const float* __restrict__ meanv,
        const float* __restrict__ sdev, float* __restrict__ out) {
    const int p0 = blockIdx.x * 128;
    const int n0 = blockIdx.y * 64;
    const int b  = blockIdx.z;
    const int tid = threadIdx.x;
    const int lane = tid & 63;
    const int wave = tid >> 6;
    const int wm = wave >> 1;    // p-base = wm*32
    const int wn = wave & 1;     // n-base = wn*32

    __shared__ unsigned short As[2][128][72];   // 36864 B
    __shared__ unsigned short Bs[2][64][72];    // 18432 B

    const int ar = tid >> 2, ac = (tid & 3) * 16;
    const int br = tid >> 3, bc = (tid & 7) * 8;
    const unsigned short* hgb = hg + (size_t)b * N_ * ER_;
    const bool avalid = (p0 + ar < P_);
    const bool bvalid = (n0 + br < N_);

    u16x8 av0, av1, bv;
    f32x4 acc[2][2];
    #pragma unroll
    for (int i = 0; i < 2; ++i)
        #pragma unroll
        for (int j = 0; j < 2; ++j) acc[i][j] = (f32x4){0.f,0.f,0.f,0.f};

    // prologue: tile 0
    {
        av0 = (u16x8){0,0,0,0,0,0,0,0}; av1 = av0; bv = av0;
        if (avalid) {
            av0 = *(const u16x8*)&w2t[(size_t)(p0 + ar)*ER_ + ac];
            av1 = *(const u16x8*)&w2t[(size_t)(p0 + ar)*ER_ + ac + 8];
        }
        if (bvalid)
            bv = *(const u16x8*)&hgb[(size_t)(n0 + br)*ER_ + bc];
        *(u16x8*)&As[0][ar][ac]   = av0;
        *(u16x8*)&As[0][ar][ac+8] = av1;
        *(u16x8*)&Bs[0][br][bc]   = bv;
    }
    __syncthreads();

    for (int t = 0; t < 4; ++t) {
        const int cur = t & 1;
        if (t < 3) {
            int k0 = (t + 1) * 64;
            av0 = (u16x8){0,0,0,0,0,0,0,0}; av1 = av0; bv = av0;
            if (avalid) {
                av0 = *(const u16x8*)&w2t[(size_t)(p0 + ar)*ER_ + k0 + ac];
                av1 = *(const u16x8*)&w2t[(size_t)(p0 + ar)*ER_ + k0 + ac + 8];
            }
            if (bvalid)
                bv = *(const u16x8*)&hgb[(size_t)(n0 + br)*ER_ + k0 + bc];
        }
        #pragma unroll
        for (int kc = 0; kc < 2; ++kc) {
            bf16x8 af[2], bfv[2];
            #pragma unroll
            for (int fm = 0; fm < 2; ++fm)
                af[fm] = *(const bf16x8*)&As[cur][wm*32 + fm*16 + (lane & 15)][kc*32 + (lane >> 4)*8];
            #pragma unroll
            for (int fn = 0; fn < 2; ++fn)
                bfv[fn] = *(const bf16x8*)&Bs[cur][wn*32 + fn*16 + (lane & 15)][kc*32 + (lane >> 4)*8];
            #pragma unroll
            for (int fm = 0; fm < 2; ++fm)
                #pragma unroll
                for (int fn = 0; fn < 2; ++fn)
                    acc[fm][fn] = __builtin_amdgcn_mfma_f32_16x16x32_bf16(af[fm], bfv[fn], acc[fm][fn], 0, 0, 0);
        }
        if (t < 3) {
            *(u16x8*)&As[cur^1][ar][ac]   = av0;
            *(u16x8*)&As[cur^1][ar][ac+8] = av1;
            *(u16x8*)&Bs[cur^1][br][bc]   = bv;
        }
        __syncthreads();
    }

    // epilogue
    #pragma unroll
    for (int fn = 0; fn < 2; ++fn) {
        int nl = wn*32 + fn*16 + (lane & 15);
        int n = n0 + nl;
        if (n < N_) {
            float mean = meanv[b*N_ + n];
            float sd   = sdev[b*N_ + n];
            #pragma unroll
            for (int fm = 0; fm < 2; ++fm) {
                int pb = p0 + wm*32 + fm*16 + (lane >> 4)*4;
                #pragma unroll
                for (int j = 0; j < 4; ++j) {
                    int p = pb + j;
                    if (p < P_) {
                        float bg = biasgT[(size_t)p*N_ + n];
                        out[((size_t)b*P_ + p)*N_ + n] = acc[fm][fn][j] + bg*sd + mean;
                    }
                }
            }
        }
    }
}

extern "C" void kernel_launch(void* const* d_in, const int* in_sizes, int n_in,
                              void* d_out, int out_size, void* d_ws, size_t ws_size,
                              hipStream_t stream) {
    const float* x     = (const float*)d_in[0];
    const float* ident = (const float*)d_in[1];
    const float* rw1   = (const float*)d_in[2];
    const float* rb1   = (const float*)d_in[3];
    const float* rw2   = (const float*)d_in[4];
    const float* rb2   = (const float*)d_in[5];
    const float* w1    = (const float*)d_in[6];
    const float* w2    = (const float*)d_in[7];
    const float* bias  = (const float*)d_in[8];
    float* out = (float*)d_out;
    float* ws  = (float*)d_ws;

    float* meanv  = ws + OFF_MEAN;
    float* sdev   = ws + OFF_SDEV;
    float* gate   = ws + OFF_GATE;
    float* cs1    = ws + OFF_CS1;
    float* biasgT = ws + OFF_BIASGT;
    unsigned short* w1k = (unsigned short*)(ws + OFF_W1K);
    unsigned short* w2t = (unsigned short*)(ws + OFF_W2T);
    unsigned short* hg  = (unsigned short*)(ws + OFF_HG);

    router_kernel<<<N_, 64, 0, stream>>>(ident, rw1, rb1, rw2, rb2, gate);
    prep_kernel<<<1960, 256, 0, stream>>>(w1, w2, gate, bias, w1k, w2t, cs1, biasgT);
    gemm1_kernel<<<dim3(6, B_), 512, 0, stream>>>(x, w1k, gate, cs1, meanv, sdev, hg);
    gemm2_kernel<<<dim3(6, 6, B_), 512, 0, stream>>>(hg, w2t, biasgT, meanv, sdev, out);
}